// Round 10
// baseline (317.303 us; speedup 1.0000x reference)
//
#include <hip/hip_runtime.h>
#include <cstdint>
#include <cstddef>

typedef __attribute__((ext_vector_type(8))) short short8;
typedef __attribute__((ext_vector_type(8))) unsigned short ushort8;
typedef __attribute__((ext_vector_type(4))) float f32x4;
typedef __attribute__((ext_vector_type(8))) _Float16 half8;
typedef __attribute__((ext_vector_type(4))) _Float16 half4;
typedef __attribute__((ext_vector_type(2))) __fp16 fp16x2;

#define DEV static __device__ __forceinline__

DEV unsigned short f2bf(float x) {
  union { float f; unsigned u; } v; v.f = x;
  unsigned r = v.u + 0x7fffu + ((v.u >> 16) & 1u);
  return (unsigned short)(r >> 16);
}
DEV unsigned pack2bf(float lo, float hi) {
  union { float f; unsigned u; } a, b; a.f = lo; b.f = hi;
  return __builtin_amdgcn_perm(b.u + 0x8000u, a.u + 0x8000u, 0x07060302u);
}
DEV f32x4 mfma16(short8 a, short8 b, f32x4 c) {
  return __builtin_amdgcn_mfma_f32_16x16x32_bf16(a, b, c, 0, 0, 0);
}
DEV f32x4 mfma16h(half8 a, half8 b, f32x4 c) {
  return __builtin_amdgcn_mfma_f32_16x16x32_f16(a, b, c, 0, 0, 0);
}
DEV f32x4 mfma16k(half4 a, half4 b, f32x4 c) {
  return __builtin_amdgcn_mfma_f32_16x16x16f16(a, b, c, 0, 0, 0);
}

// async global->LDS, 16B per lane; LDS dst = wave-uniform base + lane*16
typedef __attribute__((address_space(1))) unsigned int g_u32;
typedef __attribute__((address_space(3))) unsigned int l_u32;
DEV void glds16(const unsigned short* g, unsigned short* l) {
  __builtin_amdgcn_global_load_lds((g_u32*)g, (l_u32*)l, 16, 0, 0);
}

constexpr int Bc = 4, Nc = 2048, Dc = 1024, Hc = 16, DKc = 16, DVc = 64, DIc = 1280;
constexpr int Mc = Bc * Nc;  // 8192

// ---------------- merged prep: X->bf16 + 3 weight transposes ----------------
__global__ __launch_bounds__(256) void prep_kernel(const float* __restrict__ X,
                                                   unsigned short* __restrict__ Xb,
                                                   const float* __restrict__ Wqg,
                                                   unsigned short* __restrict__ WqgT,
                                                   const float* __restrict__ Wkv,
                                                   unsigned short* __restrict__ WkvT,
                                                   const float* __restrict__ Wout,
                                                   unsigned short* __restrict__ WoutT) {
  __shared__ unsigned short tsh[64][72];
  int bid = blockIdx.x, tid = threadIdx.x;
  if (bid < 4096) {
    int i = bid * 256 + tid;
    const float4* p = (const float4*)(X + (size_t)i * 8);
    float4 a = p[0], b = p[1];
    ushort8 o;
    o[0] = f2bf(a.x); o[1] = f2bf(a.y); o[2] = f2bf(a.z); o[3] = f2bf(a.w);
    o[4] = f2bf(b.x); o[5] = f2bf(b.y); o[6] = f2bf(b.z); o[7] = f2bf(b.w);
    *(ushort8*)(Xb + (size_t)i * 8) = o;
    return;
  }
  const float* W; unsigned short* WT; int K, N, tb;
  if (bid < 4416)      { W = Wqg;  WT = WqgT;  K = Dc; N = DIc; tb = bid - 4096; }
  else if (bid < 4736) { W = Wkv;  WT = WkvT;  K = Dc; N = DIc; tb = bid - 4416; }
  else                 { W = Wout; WT = WoutT; K = Dc; N = Dc;  tb = bid - 4736; }
  int k0 = (tb & 15) * 64, n0 = (tb >> 4) * 64;
#pragma unroll
  for (int it = 0; it < 16; ++it) {
    int f = it * 256 + tid;
    int r = f >> 6, c = f & 63;
    tsh[c][r] = f2bf(W[(size_t)(k0 + r) * N + n0 + c]);
  }
  __syncthreads();
#pragma unroll
  for (int it = 0; it < 16; ++it) {
    int f = it * 256 + tid;
    int r = f >> 6, c = f & 63;
    WT[(size_t)(n0 + r) * K + k0 + c] = tsh[r][c];
  }
}

// ---------------- fused projection GEMM: C = Xbf * [WqgT | WkvT]^T ----------------
// R9: XCD-chunked block swizzle (T1). R10: fp16 output (1 VALU/elem convert).
__global__ __launch_bounds__(256) void gemm_proj(const unsigned short* __restrict__ A,
                                                 const unsigned short* __restrict__ BT,
                                                 unsigned short* __restrict__ QG,
                                                 unsigned short* __restrict__ KV,
                                                 int Kq) {
  __shared__ unsigned short As[128 * 64];
  __shared__ unsigned short Bs[128 * 64];
  int L = blockIdx.x;                 // 0..1279; HW round-robins L%8 across XCDs
  int xcd = L & 7, idx = L >> 3;      // idx 0..159
  int brow = xcd * 8 + (idx & 7);     // 0..63  (8-row band per XCD)
  int bcol = idx >> 3;                // 0..19
  int row0 = brow * 128, col0 = bcol * 128;
  int tid = threadIdx.x, lane = tid & 63, wave = tid >> 6;
  int wm = wave >> 1, wn = wave & 1;
  int ql = lane >> 4, l16 = lane & 15;
  int r8 = lane >> 3, cbl = (lane & 7) ^ r8;

  unsigned short* dst = (col0 >= DIc) ? KV : QG;
  int c0l = (col0 >= DIc) ? col0 - DIc : col0;

  const unsigned short* gA = A + (size_t)(row0 + wave * 32 + r8) * Kq + cbl * 8;
  const unsigned short* gB = BT + (size_t)(col0 + wave * 32 + r8) * Kq + cbl * 8;

  f32x4 acc[4][4];
#pragma unroll
  for (int i = 0; i < 4; i++)
#pragma unroll
    for (int j = 0; j < 4; j++) acc[i][j] = (f32x4){0.f, 0.f, 0.f, 0.f};

  for (int k0 = 0; k0 < Kq; k0 += 64) {
    __syncthreads();
#pragma unroll
    for (int i = 0; i < 4; ++i) {
      glds16(gA + (size_t)(i * 8) * Kq + k0, &As[(wave * 32 + i * 8) * 64]);
      glds16(gB + (size_t)(i * 8) * Kq + k0, &Bs[(wave * 32 + i * 8) * 64]);
    }
    __syncthreads();
#pragma unroll
    for (int kk = 0; kk < 64; kk += 32) {
      short8 af[4], bfr[4];
#pragma unroll
      for (int t = 0; t < 4; t++) {
        int row = wm * 64 + t * 16 + l16;
        int cb = (kk >> 3) + ql;
        af[t] = *(const short8*)&As[row * 64 + ((cb ^ (row & 7)) << 3)];
      }
#pragma unroll
      for (int t = 0; t < 4; t++) {
        int row = wn * 64 + t * 16 + l16;
        int cb = (kk >> 3) + ql;
        bfr[t] = *(const short8*)&Bs[row * 64 + ((cb ^ (row & 7)) << 3)];
      }
#pragma unroll
      for (int i = 0; i < 4; i++)
#pragma unroll
        for (int j = 0; j < 4; j++) acc[i][j] = mfma16(af[i], bfr[j], acc[i][j]);
    }
  }
#pragma unroll
  for (int i = 0; i < 4; i++)
#pragma unroll
    for (int j = 0; j < 4; j++)
#pragma unroll
      for (int r = 0; r < 4; r++) {
        int rr = row0 + wm * 64 + i * 16 + ql * 4 + r;
        int cc = c0l + wn * 64 + j * 16 + l16;
        union { _Float16 h; unsigned short us; } cv;
        cv.h = (_Float16)acc[i][j][r];
        dst[(size_t)rr * DIc + cc] = cv.us;
      }
}

// ---------------- C[M][N] = A[M][K] * BT[N][K]^T (final GEMM, fp32 out) ----------------
__global__ __launch_bounds__(256) void gemm_glds(const unsigned short* __restrict__ A,
                                                 const unsigned short* __restrict__ BT,
                                                 float* __restrict__ Cout,
                                                 int Mq, int Nq, int Kq) {
  __shared__ unsigned short As[128 * 64];
  __shared__ unsigned short Bs[128 * 64];
  int L = blockIdx.x;                 // 0..511
  int xcd = L & 7, idx = L >> 3;      // idx 0..63
  int brow = xcd * 8 + (idx & 7);     // 0..63
  int bcol = idx >> 3;                // 0..7
  int row0 = brow * 128, col0 = bcol * 128;
  int tid = threadIdx.x, lane = tid & 63, wave = tid >> 6;
  int wm = wave >> 1, wn = wave & 1;
  int ql = lane >> 4, l16 = lane & 15;
  int r8 = lane >> 3, cbl = (lane & 7) ^ r8;

  const unsigned short* gA = A + (size_t)(row0 + wave * 32 + r8) * Kq + cbl * 8;
  const unsigned short* gB = BT + (size_t)(col0 + wave * 32 + r8) * Kq + cbl * 8;

  f32x4 acc[4][4];
#pragma unroll
  for (int i = 0; i < 4; i++)
#pragma unroll
    for (int j = 0; j < 4; j++) acc[i][j] = (f32x4){0.f, 0.f, 0.f, 0.f};

  for (int k0 = 0; k0 < Kq; k0 += 64) {
    __syncthreads();
#pragma unroll
    for (int i = 0; i < 4; ++i) {
      glds16(gA + (size_t)(i * 8) * Kq + k0, &As[(wave * 32 + i * 8) * 64]);
      glds16(gB + (size_t)(i * 8) * Kq + k0, &Bs[(wave * 32 + i * 8) * 64]);
    }
    __syncthreads();
#pragma unroll
    for (int kk = 0; kk < 64; kk += 32) {
      short8 af[4], bfr[4];
#pragma unroll
      for (int t = 0; t < 4; t++) {
        int row = wm * 64 + t * 16 + l16;
        int cb = (kk >> 3) + ql;
        af[t] = *(const short8*)&As[row * 64 + ((cb ^ (row & 7)) << 3)];
      }
#pragma unroll
      for (int t = 0; t < 4; t++) {
        int row = wn * 64 + t * 16 + l16;
        int cb = (kk >> 3) + ql;
        bfr[t] = *(const short8*)&Bs[row * 64 + ((cb ^ (row & 7)) << 3)];
      }
#pragma unroll
      for (int i = 0; i < 4; i++)
#pragma unroll
        for (int j = 0; j < 4; j++) acc[i][j] = mfma16(af[i], bfr[j], acc[i][j]);
    }
  }
#pragma unroll
  for (int i = 0; i < 4; i++)
#pragma unroll
    for (int j = 0; j < 4; j++)
#pragma unroll
      for (int r = 0; r < 4; r++) {
        int rr = row0 + wm * 64 + i * 16 + ql * 4 + r;
        int cc = col0 + wn * 64 + j * 16 + l16;
        Cout[(size_t)rr * Nq + cc] = acc[i][j][r];
      }
}

// ---------------- per-head normalize -> fp16 (QG/KV fp16 in) ----------------
__global__ __launch_bounds__(256) void norm_kernel(const unsigned short* __restrict__ QG,
                                                   const unsigned short* __restrict__ KV,
                                                   unsigned short* __restrict__ Qn,   // fp16 [bh][n][16]
                                                   unsigned short* __restrict__ Kn,   // fp16 [bh][n][16]
                                                   unsigned short* __restrict__ Vtg)  // fp16 [bh][d][n]
{
  int g = blockIdx.x * 256 + threadIdx.x;
  int n = g & (Nc - 1), bh = g >> 11;
  int h = bh & 15, b = bh >> 4;
  size_t src = ((size_t)(b * Nc + n)) * DIc + h * 80;

  {
    half8 u0 = *(const half8*)&QG[src];
    half8 u1 = *(const half8*)&QG[src + 8];
    float q[16], ss = 0.f;
#pragma unroll
    for (int i = 0; i < 8; i++) { q[i] = (float)u0[i]; q[8 + i] = (float)u1[i]; }
#pragma unroll
    for (int i = 0; i < 16; i++) ss += q[i] * q[i];
    float sc = 1.f / fmaxf(sqrtf(ss), 1e-12f);
    half8 o0, o1;
#pragma unroll
    for (int i = 0; i < 8; i++) { o0[i] = (_Float16)(q[i] * sc); o1[i] = (_Float16)(q[8 + i] * sc); }
    size_t dst = ((size_t)bh * Nc + n) * 16;
    *(half8*)&Qn[dst] = o0;
    *(half8*)&Qn[dst + 8] = o1;
  }
  {
    half8 u0 = *(const half8*)&KV[src];
    half8 u1 = *(const half8*)&KV[src + 8];
    float q[16], ss = 0.f;
#pragma unroll
    for (int i = 0; i < 8; i++) { q[i] = (float)u0[i]; q[8 + i] = (float)u1[i]; }
#pragma unroll
    for (int i = 0; i < 16; i++) ss += q[i] * q[i];
    float sc = 1.f / fmaxf(sqrtf(ss), 1e-12f);
    half8 o0, o1;
#pragma unroll
    for (int i = 0; i < 8; i++) { o0[i] = (_Float16)(q[i] * sc); o1[i] = (_Float16)(q[8 + i] * sc); }
    size_t dst = ((size_t)bh * Nc + n) * 16;
    *(half8*)&Kn[dst] = o0;
    *(half8*)&Kn[dst + 8] = o1;
  }
  {
    half8 u[8];
#pragma unroll
    for (int i = 0; i < 8; i++) u[i] = *(const half8*)&KV[src + 16 + i * 8];
    float ss = 0.f;
#pragma unroll
    for (int i = 0; i < 8; i++)
#pragma unroll
      for (int j = 0; j < 8; j++) { float x = (float)u[i][j]; ss += x * x; }
    float sc = 1.f / fmaxf(sqrtf(ss), 1e-12f);
#pragma unroll
    for (int i = 0; i < 8; i++)
#pragma unroll
      for (int j = 0; j < 8; j++) {
        int d = i * 8 + j;
        union { _Float16 h; unsigned short us; } cv;
        cv.h = (_Float16)((float)u[i][j] * sc);
        Vtg[((size_t)bh * DVc + d) * Nc + n] = cv.us;
      }
  }
}

// ---------------- relu^2 attention, fp16 datapath ----------------
// R15 (resubmitted after container-infra failure; never executed): V LDS
// staging DROPPED (Common-mistake #7 / m169). Each block's K+V (320KB) is
// L2-resident (same-bh q-blocks land on one XCD via the gid%8 swizzle;
// 8 bh x 320KB = 2.5MB < 4MB L2). PV A-frags load DIRECTLY from Vtg as two
// 8B global loads (keys p*32+ql*4.. and +16 -- same permuted-key bijection
// as the LDS path, no shuffle). Removes: all 16 main-loop barriers (the
// vmcnt-drain stall = the 60% idle R14 measured), glds16s, 4.19M bank
// conflicts, 32KB->17KB LDS. Main loop = straight-line per-wave code; VGPR
// can grow freely (grid caps at 2 waves/SIMD). Keeps: 64 q/wave amortization
// (R14), K=16 S-MFMA, kf dbuf, setprio.
__global__ __launch_bounds__(256, 2) void attn_kernel(const unsigned short* __restrict__ Qn,
                                                      const unsigned short* __restrict__ Kn,
                                                      const unsigned short* __restrict__ Vtg,
                                                      const unsigned short* __restrict__ QG,
                                                      unsigned short* __restrict__ outpre) {
  __shared__ unsigned short shm[128 * 68];  // epilogue 'of' only (17KB)

  int gid = blockIdx.x;                 // 0..511
  int xcd = gid & 7, slot = gid >> 3;   // slot 0..63
  int bh = xcd * 8 + (slot & 7);
  int q0 = (slot >> 3) * 256;
  int b = bh >> 4, h = bh & 15;
  int tid = threadIdx.x, lane = tid & 63, wave = tid >> 6;
  int ql = lane >> 4, l16 = lane & 15;
  int qw0 = q0 + wave * 64;

  // Q fragments (B-operand of S-mfma, K=16), resident: q = qw0 + qt*16 + l16
  half4 qf[4];
#pragma unroll
  for (int qt = 0; qt < 4; ++qt)
    qf[qt] = *(const half4*)&Qn[((size_t)bh * Nc + qw0 + qt * 16 + l16) * 16 + ql * 4];

  const unsigned short* krow = Kn + (size_t)bh * Nc * 16;
  const unsigned short* vbase = Vtg + ((size_t)bh * DVc) * Nc;
  // per-thread V base: A-frag lane(ql,l16) reads row d = dt*16+l16,
  // keys k0 + p*32 + ql*4 (8B) and +16 (8B) -- permuted-key bijection.
  const unsigned short* vrow0 = vbase + (size_t)l16 * Nc + ql * 4;

  f32x4 acc[4][4];  // [dt][qt] -- literal-indexed everywhere
#pragma unroll
  for (int dt = 0; dt < 4; dt++)
#pragma unroll
    for (int qt = 0; qt < 4; qt++) acc[dt][qt] = (f32x4){0.f, 0.f, 0.f, 0.f};

  half4 kfA[8], kfB[8];

  // ---- prologue: kf tile 0 -> kfA ----
#pragma unroll
  for (int kh = 0; kh < 8; ++kh)
    kfA[kh] = *(const half4*)&krow[(size_t)(kh * 16 + l16) * 16 + ql * 4];

#define TILE_BODY(KT, KFU, KFN, LN)                                                      \
  {                                                                                      \
    int k0 = (KT) * 128;                                                                 \
    if (LN) {                                                                            \
      int kn0 = k0 + 128;                                                                \
      _Pragma("unroll") for (int kh = 0; kh < 8; ++kh)                                   \
        KFN[kh] = *(const half4*)&krow[(size_t)(kn0 + kh * 16 + l16) * 16 + ql * 4];     \
    }                                                                                    \
    __builtin_amdgcn_s_setprio(1);                                                       \
    _Pragma("unroll") for (int p = 0; p < 4; ++p) { /* 32-key group */                   \
      f32x4 c0[4], c1[4];                                                                \
      _Pragma("unroll") for (int qt = 0; qt < 4; ++qt) {                                 \
        c0[qt] = mfma16k(KFU[2 * p],     qf[qt], (f32x4){0.f, 0.f, 0.f, 0.f});           \
        c1[qt] = mfma16k(KFU[2 * p + 1], qf[qt], (f32x4){0.f, 0.f, 0.f, 0.f});           \
      }                                                                                  \
      half8 pf[4];                                                                       \
      _Pragma("unroll") for (int qt = 0; qt < 4; ++qt) {                                 \
        union { half8 hh; fp16x2 p2[4]; } w;                                             \
        fp16x2 t0 = __builtin_amdgcn_cvt_pkrtz(c0[qt][0], c0[qt][1]);                    \
        fp16x2 t1 = __builtin_amdgcn_cvt_pkrtz(c0[qt][2], c0[qt][3]);                    \
        fp16x2 t2 = __builtin_amdgcn_cvt_pkrtz(c1[qt][0], c1[qt][1]);                    \
        fp16x2 t3 = __builtin_amdgcn_cvt_pkrtz(c1[qt][2], c1[qt][3]);                    \
        const fp16x2 hz = {(__fp16)0, (__fp16)0};                                        \
        t0 = __builtin_elementwise_max(t0, hz); w.p2[0] = t0 * t0;                       \
        t1 = __builtin_elementwise_max(t1, hz); w.p2[1] = t1 * t1;                       \
        t2 = __builtin_elementwise_max(t2, hz); w.p2[2] = t2 * t2;                       \
        t3 = __builtin_elementwise_max(t3, hz); w.p2[3] = t3 * t3;                       \
        pf[qt] = w.hh;                                                                   \
      }                                                                                  \
      /* PV: A-frags direct from L2-resident Vtg (two 8B loads per dt) */                \
      _Pragma("unroll") for (int dt = 0; dt < 4; ++dt) {                                 \
        const unsigned short* vp = vrow0 + (size_t)(dt * 16) * Nc + k0 + p * 32;         \
        union { half8 s; uint4 u; } vf;                                                  \
        uint2 va = *(const uint2*)vp;                                                    \
        uint2 vb2 = *(const uint2*)(vp + 16);                                            \
        vf.u.x = va.x; vf.u.y = va.y; vf.u.z = vb2.x; vf.u.w = vb2.y;                    \
        _Pragma("unroll") for (int qt = 0; qt < 4; ++qt)                                 \
          acc[dt][qt] = mfma16h(vf.s, pf[qt], acc[dt][qt]);                              \
      }                                                                                  \
    }                                                                                    \
    __builtin_amdgcn_s_setprio(0);                                                       \
  }

#pragma unroll 1
  for (int kt2 = 0; kt2 < 8; ++kt2) {
    int kte = kt2 * 2;
    TILE_BODY(kte, kfA, kfB, 1)
    TILE_BODY(kte + 1, kfB, kfA, (kt2 < 7))
  }
#undef TILE_BODY

  // epilogue in two 128-row halves; of[128][68] (17KB). Fully unrolled
  // (hh, qi compile-time) so acc stays in registers (rule #20).
  unsigned short(*of)[68] = (unsigned short(*)[68])shm;
#pragma unroll
  for (int hh = 0; hh < 2; ++hh) {
    __syncthreads();  // half 1: previous half's reads done before overwrite
#pragma unroll
    for (int qi = 0; qi < 2; ++qi) {
      // qt = hh*2 + qi (compile-time); lane(ql,l16) holds O[q][d = dt*16+ql*4+r]
      float ss = 0.f;
#pragma unroll
      for (int dt = 0; dt < 4; ++dt)
#pragma unroll
        for (int r = 0; r < 4; ++r) {
          float v = acc[dt][hh * 2 + qi][r];
          ss += v * v;
        }
      ss += __shfl_xor(ss, 16, 64);
      ss += __shfl_xor(ss, 32, 64);
      float nrm = sqrtf(ss);
      float sc = tanhf(nrm) / fmaxf(nrm, 1e-12f);
      int q = qw0 + (hh * 2 + qi) * 16 + l16;
      size_t gbase = ((size_t)(b * Nc + q)) * DIc + h * 80 + DKc;  // gate slice (fp16)
#pragma unroll
      for (int dt = 0; dt < 4; ++dt) {
        uint2 gu = *(const uint2*)&QG[gbase + dt * 16 + ql * 4];
        union { uint2 u; _Float16 hv[4]; } gv; gv.u = gu;
        float o[4];
#pragma unroll
        for (int r = 0; r < 4; ++r) {
          float x = (float)gv.hv[r];
          float av = acc[dt][hh * 2 + qi][r];
          float s = x / (1.f + __expf(-x));
          float e2 = __expf(2.f * s);
          float g = 1.f - 2.f / (e2 + 1.f);  // tanh(s)
          o[r] = av * sc * g;
        }
        uint2 w;
        w.x = pack2bf(o[0], o[1]);
        w.y = pack2bf(o[2], o[3]);
        *(uint2*)&of[wave * 32 + qi * 16 + l16][dt * 16 + ql * 4] = w;
      }
    }
    __syncthreads();
    {
      int row = tid >> 1, cb = (tid & 1) * 32;
      int q = q0 + (row >> 5) * 64 + hh * 32 + (row & 31);
      size_t obase = ((size_t)(b * Nc + q)) * (Hc * DVc) + h * DVc + cb;
#pragma unroll
      for (int i = 0; i < 4; ++i)
        *(ushort8*)&outpre[obase + i * 8] = *(const ushort8*)&of[row][cb + i * 8];
    }
  }
}

extern "C" void kernel_launch(void* const* d_in, const int* in_sizes, int n_in,
                              void* d_out, int out_size, void* d_ws, size_t ws_size,
                              hipStream_t stream) {
  const float* X = (const float*)d_in[0];     // (4,2048,1024)
  const float* Wqg = (const float*)d_in[1];   // (1024,1280)
  const float* Wkv = (const float*)d_in[2];   // (1024,1280)
  const float* Wout = (const float*)d_in[3];  // (1024,1024)
  float* out = (float*)d_out;
  (void)in_sizes; (void)n_in; (void)out_size; (void)ws_size;

  char* ws = (char*)d_ws;
  size_t off = 0;
  auto alloc = [&](size_t bytes) {
    void* p = ws + off;
    off += (bytes + 255) & ~(size_t)255;
    return p;
  };
  unsigned short* Xbf   = (unsigned short*)alloc((size_t)Mc * Dc * 2);            // 16 MB
  unsigned short* WqgT  = (unsigned short*)alloc((size_t)DIc * Dc * 2);           // 2.5 MB (WkvT MUST follow contiguously)
  unsigned short* WkvT  = (unsigned short*)alloc((size_t)DIc * Dc * 2);
  unsigned short* WoutT = (unsigned short*)alloc((size_t)Dc * Dc * 2);            // 2 MB
  unsigned short* QG    = (unsigned short*)alloc((size_t)Mc * DIc * 2);           // 20 MB (fp16)
  unsigned short* KV    = (unsigned short*)alloc((size_t)Mc * DIc * 2);           // 20 MB (fp16)
  unsigned short* Qn    = (unsigned short*)alloc((size_t)Bc * Hc * Nc * 16 * 2);  // 4 MB (fp16, unpadded)
  unsigned short* Kn    = (unsigned short*)alloc((size_t)Bc * Hc * Nc * 16 * 2);  // 4 MB
  unsigned short* Vtg   = (unsigned short*)alloc((size_t)Bc * Hc * Nc * DVc * 2); // 16 MB (fp16)
  unsigned short* outpre = Xbf;  // Xbf dead after projection GEMM; same size

  prep_kernel<<<4992, 256, 0, stream>>>(X, Xbf, Wqg, WqgT, Wkv, WkvT, Wout, WoutT);
  gemm_proj<<<Mc / 128 * (2 * DIc / 128), 256, 0, stream>>>(Xbf, WqgT, QG, KV, Dc);
  norm_kernel<<<(Mc * Hc) / 256, 256, 0, stream>>>(QG, KV, Qn, Kn, Vtg);
  attn_kernel<<<512, 256, 0, stream>>>(Qn, Kn, Vtg, QG, outpre);
  gemm_glds<<<Mc / 128 * (Dc / 128), 256, 0, stream>>>(outpre, WoutT, out, Mc, Dc, Dc);
}

// Round 11
// 235.690 us; speedup vs baseline: 1.3463x; 1.3463x over previous
//
#include <hip/hip_runtime.h>
#include <cstdint>
#include <cstddef>

typedef __attribute__((ext_vector_type(8))) short short8;
typedef __attribute__((ext_vector_type(8))) unsigned short ushort8;
typedef __attribute__((ext_vector_type(4))) float f32x4;
typedef __attribute__((ext_vector_type(8))) _Float16 half8;
typedef __attribute__((ext_vector_type(4))) _Float16 half4;
typedef __attribute__((ext_vector_type(2))) __fp16 fp16x2;

#define DEV static __device__ __forceinline__

DEV unsigned short f2bf(float x) {
  union { float f; unsigned u; } v; v.f = x;
  unsigned r = v.u + 0x7fffu + ((v.u >> 16) & 1u);
  return (unsigned short)(r >> 16);
}
DEV unsigned pack2bf(float lo, float hi) {
  union { float f; unsigned u; } a, b; a.f = lo; b.f = hi;
  return __builtin_amdgcn_perm(b.u + 0x8000u, a.u + 0x8000u, 0x07060302u);
}
DEV f32x4 mfma16(short8 a, short8 b, f32x4 c) {
  return __builtin_amdgcn_mfma_f32_16x16x32_bf16(a, b, c, 0, 0, 0);
}
DEV f32x4 mfma16h(half8 a, half8 b, f32x4 c) {
  return __builtin_amdgcn_mfma_f32_16x16x32_f16(a, b, c, 0, 0, 0);
}
DEV f32x4 mfma16k(half4 a, half4 b, f32x4 c) {
  return __builtin_amdgcn_mfma_f32_16x16x16f16(a, b, c, 0, 0, 0);
}

// async global->LDS, 16B per lane; LDS dst = wave-uniform base + lane*16
typedef __attribute__((address_space(1))) unsigned int g_u32;
typedef __attribute__((address_space(3))) unsigned int l_u32;
DEV void glds16(const unsigned short* g, unsigned short* l) {
  __builtin_amdgcn_global_load_lds((g_u32*)g, (l_u32*)l, 16, 0, 0);
}

constexpr int Bc = 4, Nc = 2048, Dc = 1024, Hc = 16, DKc = 16, DVc = 64, DIc = 1280;
constexpr int Mc = Bc * Nc;  // 8192

// ---------------- merged prep: X->bf16 + 3 weight transposes ----------------
__global__ __launch_bounds__(256) void prep_kernel(const float* __restrict__ X,
                                                   unsigned short* __restrict__ Xb,
                                                   const float* __restrict__ Wqg,
                                                   unsigned short* __restrict__ WqgT,
                                                   const float* __restrict__ Wkv,
                                                   unsigned short* __restrict__ WkvT,
                                                   const float* __restrict__ Wout,
                                                   unsigned short* __restrict__ WoutT) {
  __shared__ unsigned short tsh[64][72];
  int bid = blockIdx.x, tid = threadIdx.x;
  if (bid < 4096) {
    int i = bid * 256 + tid;
    const float4* p = (const float4*)(X + (size_t)i * 8);
    float4 a = p[0], b = p[1];
    ushort8 o;
    o[0] = f2bf(a.x); o[1] = f2bf(a.y); o[2] = f2bf(a.z); o[3] = f2bf(a.w);
    o[4] = f2bf(b.x); o[5] = f2bf(b.y); o[6] = f2bf(b.z); o[7] = f2bf(b.w);
    *(ushort8*)(Xb + (size_t)i * 8) = o;
    return;
  }
  const float* W; unsigned short* WT; int K, N, tb;
  if (bid < 4416)      { W = Wqg;  WT = WqgT;  K = Dc; N = DIc; tb = bid - 4096; }
  else if (bid < 4736) { W = Wkv;  WT = WkvT;  K = Dc; N = DIc; tb = bid - 4416; }
  else                 { W = Wout; WT = WoutT; K = Dc; N = Dc;  tb = bid - 4736; }
  int k0 = (tb & 15) * 64, n0 = (tb >> 4) * 64;
#pragma unroll
  for (int it = 0; it < 16; ++it) {
    int f = it * 256 + tid;
    int r = f >> 6, c = f & 63;
    tsh[c][r] = f2bf(W[(size_t)(k0 + r) * N + n0 + c]);
  }
  __syncthreads();
#pragma unroll
  for (int it = 0; it < 16; ++it) {
    int f = it * 256 + tid;
    int r = f >> 6, c = f & 63;
    WT[(size_t)(n0 + r) * K + k0 + c] = tsh[r][c];
  }
}

// ---------------- fused projection GEMM: C = Xbf * [WqgT | WkvT]^T ----------------
// R9: XCD-chunked block swizzle (T1). R10: fp16 output (1 VALU/elem convert).
__global__ __launch_bounds__(256) void gemm_proj(const unsigned short* __restrict__ A,
                                                 const unsigned short* __restrict__ BT,
                                                 unsigned short* __restrict__ QG,
                                                 unsigned short* __restrict__ KV,
                                                 int Kq) {
  __shared__ unsigned short As[128 * 64];
  __shared__ unsigned short Bs[128 * 64];
  int L = blockIdx.x;                 // 0..1279; HW round-robins L%8 across XCDs
  int xcd = L & 7, idx = L >> 3;      // idx 0..159
  int brow = xcd * 8 + (idx & 7);     // 0..63  (8-row band per XCD)
  int bcol = idx >> 3;                // 0..19
  int row0 = brow * 128, col0 = bcol * 128;
  int tid = threadIdx.x, lane = tid & 63, wave = tid >> 6;
  int wm = wave >> 1, wn = wave & 1;
  int ql = lane >> 4, l16 = lane & 15;
  int r8 = lane >> 3, cbl = (lane & 7) ^ r8;

  unsigned short* dst = (col0 >= DIc) ? KV : QG;
  int c0l = (col0 >= DIc) ? col0 - DIc : col0;

  const unsigned short* gA = A + (size_t)(row0 + wave * 32 + r8) * Kq + cbl * 8;
  const unsigned short* gB = BT + (size_t)(col0 + wave * 32 + r8) * Kq + cbl * 8;

  f32x4 acc[4][4];
#pragma unroll
  for (int i = 0; i < 4; i++)
#pragma unroll
    for (int j = 0; j < 4; j++) acc[i][j] = (f32x4){0.f, 0.f, 0.f, 0.f};

  for (int k0 = 0; k0 < Kq; k0 += 64) {
    __syncthreads();
#pragma unroll
    for (int i = 0; i < 4; ++i) {
      glds16(gA + (size_t)(i * 8) * Kq + k0, &As[(wave * 32 + i * 8) * 64]);
      glds16(gB + (size_t)(i * 8) * Kq + k0, &Bs[(wave * 32 + i * 8) * 64]);
    }
    __syncthreads();
#pragma unroll
    for (int kk = 0; kk < 64; kk += 32) {
      short8 af[4], bfr[4];
#pragma unroll
      for (int t = 0; t < 4; t++) {
        int row = wm * 64 + t * 16 + l16;
        int cb = (kk >> 3) + ql;
        af[t] = *(const short8*)&As[row * 64 + ((cb ^ (row & 7)) << 3)];
      }
#pragma unroll
      for (int t = 0; t < 4; t++) {
        int row = wn * 64 + t * 16 + l16;
        int cb = (kk >> 3) + ql;
        bfr[t] = *(const short8*)&Bs[row * 64 + ((cb ^ (row & 7)) << 3)];
      }
#pragma unroll
      for (int i = 0; i < 4; i++)
#pragma unroll
        for (int j = 0; j < 4; j++) acc[i][j] = mfma16(af[i], bfr[j], acc[i][j]);
    }
  }
#pragma unroll
  for (int i = 0; i < 4; i++)
#pragma unroll
    for (int j = 0; j < 4; j++)
#pragma unroll
      for (int r = 0; r < 4; r++) {
        int rr = row0 + wm * 64 + i * 16 + ql * 4 + r;
        int cc = c0l + wn * 64 + j * 16 + l16;
        union { _Float16 h; unsigned short us; } cv;
        cv.h = (_Float16)acc[i][j][r];
        dst[(size_t)rr * DIc + cc] = cv.us;
      }
}

// ---------------- C[M][N] = A[M][K] * BT[N][K]^T (final GEMM, fp32 out) ----------------
__global__ __launch_bounds__(256) void gemm_glds(const unsigned short* __restrict__ A,
                                                 const unsigned short* __restrict__ BT,
                                                 float* __restrict__ Cout,
                                                 int Mq, int Nq, int Kq) {
  __shared__ unsigned short As[128 * 64];
  __shared__ unsigned short Bs[128 * 64];
  int L = blockIdx.x;                 // 0..511
  int xcd = L & 7, idx = L >> 3;      // idx 0..63
  int brow = xcd * 8 + (idx & 7);     // 0..63
  int bcol = idx >> 3;                // 0..7
  int row0 = brow * 128, col0 = bcol * 128;
  int tid = threadIdx.x, lane = tid & 63, wave = tid >> 6;
  int wm = wave >> 1, wn = wave & 1;
  int ql = lane >> 4, l16 = lane & 15;
  int r8 = lane >> 3, cbl = (lane & 7) ^ r8;

  const unsigned short* gA = A + (size_t)(row0 + wave * 32 + r8) * Kq + cbl * 8;
  const unsigned short* gB = BT + (size_t)(col0 + wave * 32 + r8) * Kq + cbl * 8;

  f32x4 acc[4][4];
#pragma unroll
  for (int i = 0; i < 4; i++)
#pragma unroll
    for (int j = 0; j < 4; j++) acc[i][j] = (f32x4){0.f, 0.f, 0.f, 0.f};

  for (int k0 = 0; k0 < Kq; k0 += 64) {
    __syncthreads();
#pragma unroll
    for (int i = 0; i < 4; ++i) {
      glds16(gA + (size_t)(i * 8) * Kq + k0, &As[(wave * 32 + i * 8) * 64]);
      glds16(gB + (size_t)(i * 8) * Kq + k0, &Bs[(wave * 32 + i * 8) * 64]);
    }
    __syncthreads();
#pragma unroll
    for (int kk = 0; kk < 64; kk += 32) {
      short8 af[4], bfr[4];
#pragma unroll
      for (int t = 0; t < 4; t++) {
        int row = wm * 64 + t * 16 + l16;
        int cb = (kk >> 3) + ql;
        af[t] = *(const short8*)&As[row * 64 + ((cb ^ (row & 7)) << 3)];
      }
#pragma unroll
      for (int t = 0; t < 4; t++) {
        int row = wn * 64 + t * 16 + l16;
        int cb = (kk >> 3) + ql;
        bfr[t] = *(const short8*)&Bs[row * 64 + ((cb ^ (row & 7)) << 3)];
      }
#pragma unroll
      for (int i = 0; i < 4; i++)
#pragma unroll
        for (int j = 0; j < 4; j++) acc[i][j] = mfma16(af[i], bfr[j], acc[i][j]);
    }
  }
#pragma unroll
  for (int i = 0; i < 4; i++)
#pragma unroll
    for (int j = 0; j < 4; j++)
#pragma unroll
      for (int r = 0; r < 4; r++) {
        int rr = row0 + wm * 64 + i * 16 + ql * 4 + r;
        int cc = col0 + wn * 64 + j * 16 + l16;
        Cout[(size_t)rr * Nq + cc] = acc[i][j][r];
      }
}

// ---------------- per-head normalize -> fp16 (QG/KV fp16 in) ----------------
__global__ __launch_bounds__(256) void norm_kernel(const unsigned short* __restrict__ QG,
                                                   const unsigned short* __restrict__ KV,
                                                   unsigned short* __restrict__ Qn,   // fp16 [bh][n][16]
                                                   unsigned short* __restrict__ Kn,   // fp16 [bh][n][16]
                                                   unsigned short* __restrict__ Vtg)  // fp16 [bh][d][n]
{
  int g = blockIdx.x * 256 + threadIdx.x;
  int n = g & (Nc - 1), bh = g >> 11;
  int h = bh & 15, b = bh >> 4;
  size_t src = ((size_t)(b * Nc + n)) * DIc + h * 80;

  {
    half8 u0 = *(const half8*)&QG[src];
    half8 u1 = *(const half8*)&QG[src + 8];
    float q[16], ss = 0.f;
#pragma unroll
    for (int i = 0; i < 8; i++) { q[i] = (float)u0[i]; q[8 + i] = (float)u1[i]; }
#pragma unroll
    for (int i = 0; i < 16; i++) ss += q[i] * q[i];
    float sc = 1.f / fmaxf(sqrtf(ss), 1e-12f);
    half8 o0, o1;
#pragma unroll
    for (int i = 0; i < 8; i++) { o0[i] = (_Float16)(q[i] * sc); o1[i] = (_Float16)(q[8 + i] * sc); }
    size_t dst = ((size_t)bh * Nc + n) * 16;
    *(half8*)&Qn[dst] = o0;
    *(half8*)&Qn[dst + 8] = o1;
  }
  {
    half8 u0 = *(const half8*)&KV[src];
    half8 u1 = *(const half8*)&KV[src + 8];
    float q[16], ss = 0.f;
#pragma unroll
    for (int i = 0; i < 8; i++) { q[i] = (float)u0[i]; q[8 + i] = (float)u1[i]; }
#pragma unroll
    for (int i = 0; i < 16; i++) ss += q[i] * q[i];
    float sc = 1.f / fmaxf(sqrtf(ss), 1e-12f);
    half8 o0, o1;
#pragma unroll
    for (int i = 0; i < 8; i++) { o0[i] = (_Float16)(q[i] * sc); o1[i] = (_Float16)(q[8 + i] * sc); }
    size_t dst = ((size_t)bh * Nc + n) * 16;
    *(half8*)&Kn[dst] = o0;
    *(half8*)&Kn[dst + 8] = o1;
  }
  {
    half8 u[8];
#pragma unroll
    for (int i = 0; i < 8; i++) u[i] = *(const half8*)&KV[src + 16 + i * 8];
    float ss = 0.f;
#pragma unroll
    for (int i = 0; i < 8; i++)
#pragma unroll
      for (int j = 0; j < 8; j++) { float x = (float)u[i][j]; ss += x * x; }
    float sc = 1.f / fmaxf(sqrtf(ss), 1e-12f);
#pragma unroll
    for (int i = 0; i < 8; i++)
#pragma unroll
      for (int j = 0; j < 8; j++) {
        int d = i * 8 + j;
        union { _Float16 h; unsigned short us; } cv;
        cv.h = (_Float16)((float)u[i][j] * sc);
        Vtg[((size_t)bh * DVc + d) * Nc + n] = cv.us;
      }
  }
}

// ---------------- relu^2 attention, fp16 datapath ----------------
// R16 = R14 restored (session best: attn 64.0us, total 236.8us).
// R15 post-mortem: dropping V's LDS staging for direct global gathers was
// 2.3x WORSE (64->145us, MfmaUtil 14, latency-bound): the PV fragment gather
// is 8B/lane scattered across 16 rows 4KB apart -- each use-site pays ~200cy
// L2 latency that 2 waves/SIMD can't hide. LDS staging is the machinery that
// converts that scatter into coalesced glds16 + ~6cy ds_reads; the barriers
// are the cheap part. (m169's de-staging won because its reads were
// row-coalesced; this one isn't.)
// Structure: QBLK=256, 4 waves x 64 q-rows, grid 512 (2 blocks/CU); async
// glds16 V double-buffer; 32 V ds_reads/tile feed 64 PV-MFMAs; K=16 S-MFMA;
// kf register double-buffer; setprio around MFMA region; fully-unrolled
// epilogue (rule #20: all acc indices compile-time).
__global__ __launch_bounds__(256, 2) void attn_kernel(const unsigned short* __restrict__ Qn,
                                                      const unsigned short* __restrict__ Kn,
                                                      const unsigned short* __restrict__ Vtg,
                                                      const unsigned short* __restrict__ QG,
                                                      unsigned short* __restrict__ outpre) {
  __shared__ unsigned short shm[2 * 64 * 128];  // vt[2][64][128] fp16 (32KB); epilogue aliases of[128][68]

  int gid = blockIdx.x;                 // 0..511
  int xcd = gid & 7, slot = gid >> 3;   // slot 0..63
  int bh = xcd * 8 + (slot & 7);
  int q0 = (slot >> 3) * 256;
  int b = bh >> 4, h = bh & 15;
  int tid = threadIdx.x, lane = tid & 63, wave = tid >> 6;
  int ql = lane >> 4, l16 = lane & 15;
  int qw0 = q0 + wave * 64;

  // Q fragments (B-operand of S-mfma, K=16), resident: q = qw0 + qt*16 + l16
  half4 qf[4];
#pragma unroll
  for (int qt = 0; qt < 4; ++qt)
    qf[qt] = *(const half4*)&Qn[((size_t)bh * Nc + qw0 + qt * 16 + l16) * 16 + ql * 4];

  const unsigned short* krow = Kn + (size_t)bh * Nc * 16;
  const unsigned short* vbase = Vtg + ((size_t)bh * DVc) * Nc;

  int lq = lane >> 4, m16 = lane & 15;
  int tsw = (l16 & 7) << 1;

  f32x4 acc[4][4];  // [dt][qt] -- every access below is literal-indexed
#pragma unroll
  for (int dt = 0; dt < 4; dt++)
#pragma unroll
    for (int qt = 0; qt < 4; qt++) acc[dt][qt] = (f32x4){0.f, 0.f, 0.f, 0.f};

  half4 kfA[8], kfB[8];

  // ---- prologue: kf tile 0 -> kfA; V tile 0 -> buf0 via async glds16 ----
#pragma unroll
  for (int kh = 0; kh < 8; ++kh)
    kfA[kh] = *(const half4*)&krow[(size_t)(kh * 16 + l16) * 16 + ql * 4];
#pragma unroll
  for (int i = 0; i < 4; ++i) {
    int r0 = i * 16 + wave * 4;
    int d = r0 + lq;
    glds16(vbase + (size_t)d * Nc + 0 + ((m16 ^ (d & 7)) << 3), &shm[r0 * 128]);
  }

#define TILE_BODY(KT, KFU, KFN, LN)                                                      \
  {                                                                                      \
    __syncthreads(); /* drains glds for this tile; all waves done reading prev buf */    \
    unsigned short* vtb = &shm[((KT) & 1) * 8192];                                       \
    if (LN) {                                                                            \
      int kn0 = ((KT) + 1) * 128;                                                        \
      unsigned short* nb = &shm[(((KT) + 1) & 1) * 8192];                                \
      _Pragma("unroll") for (int i = 0; i < 4; ++i) {                                    \
        int r0 = i * 16 + wave * 4;                                                      \
        int d = r0 + lq;                                                                 \
        glds16(vbase + (size_t)d * Nc + kn0 + ((m16 ^ (d & 7)) << 3), &nb[r0 * 128]);    \
      }                                                                                  \
      _Pragma("unroll") for (int kh = 0; kh < 8; ++kh)                                   \
        KFN[kh] = *(const half4*)&krow[(size_t)(kn0 + kh * 16 + l16) * 16 + ql * 4];     \
    }                                                                                    \
    __builtin_amdgcn_s_setprio(1);                                                       \
    _Pragma("unroll") for (int p = 0; p < 4; ++p) { /* 32-key group */                   \
      f32x4 c0[4], c1[4];                                                                \
      _Pragma("unroll") for (int qt = 0; qt < 4; ++qt) {                                 \
        c0[qt] = mfma16k(KFU[2 * p],     qf[qt], (f32x4){0.f, 0.f, 0.f, 0.f});           \
        c1[qt] = mfma16k(KFU[2 * p + 1], qf[qt], (f32x4){0.f, 0.f, 0.f, 0.f});           \
      }                                                                                  \
      half8 pf[4];                                                                       \
      _Pragma("unroll") for (int qt = 0; qt < 4; ++qt) {                                 \
        union { half8 hh; fp16x2 p2[4]; } w;                                             \
        fp16x2 t0 = __builtin_amdgcn_cvt_pkrtz(c0[qt][0], c0[qt][1]);                    \
        fp16x2 t1 = __builtin_amdgcn_cvt_pkrtz(c0[qt][2], c0[qt][3]);                    \
        fp16x2 t2 = __builtin_amdgcn_cvt_pkrtz(c1[qt][0], c1[qt][1]);                    \
        fp16x2 t3 = __builtin_amdgcn_cvt_pkrtz(c1[qt][2], c1[qt][3]);                    \
        const fp16x2 hz = {(__fp16)0, (__fp16)0};                                        \
        t0 = __builtin_elementwise_max(t0, hz); w.p2[0] = t0 * t0;                       \
        t1 = __builtin_elementwise_max(t1, hz); w.p2[1] = t1 * t1;                       \
        t2 = __builtin_elementwise_max(t2, hz); w.p2[2] = t2 * t2;                       \
        t3 = __builtin_elementwise_max(t3, hz); w.p2[3] = t3 * t3;                       \
        pf[qt] = w.hh;                                                                   \
      }                                                                                  \
      /* PV: shared V^T frags (1 load set serves 4 qt) */                                \
      int s1 = ((p * 8 + ql) ^ tsw) << 2;                                                \
      int s2 = s1 ^ 16;                                                                  \
      _Pragma("unroll") for (int dt = 0; dt < 4; ++dt) {                                 \
        const unsigned short* vrow = vtb + (dt * 16 + l16) * 128;                        \
        union { half8 s; uint4 u; } vf;                                                  \
        uint2 va = *(const uint2*)&vrow[s1];                                             \
        uint2 vb2 = *(const uint2*)&vrow[s2];                                            \
        vf.u.x = va.x; vf.u.y = va.y; vf.u.z = vb2.x; vf.u.w = vb2.y;                    \
        _Pragma("unroll") for (int qt = 0; qt < 4; ++qt)                                 \
          acc[dt][qt] = mfma16h(vf.s, pf[qt], acc[dt][qt]);                              \
      }                                                                                  \
    }                                                                                    \
    __builtin_amdgcn_s_setprio(0);                                                       \
  }

#pragma unroll 1
  for (int kt2 = 0; kt2 < 8; ++kt2) {
    int kte = kt2 * 2;
    TILE_BODY(kte, kfA, kfB, 1)
    TILE_BODY(kte + 1, kfB, kfA, (kt2 < 7))
  }
#undef TILE_BODY

  // epilogue in two 128-row halves; of[128][68] (17.4KB) aliases shm.
  // FULLY UNROLLED (hh, qi compile-time) so acc stays in registers.
  unsigned short(*of)[68] = (unsigned short(*)[68])shm;
#pragma unroll
  for (int hh = 0; hh < 2; ++hh) {
    __syncthreads();  // half 0: waves done with vt; half 1: flush of prev half done
#pragma unroll
    for (int qi = 0; qi < 2; ++qi) {
      // qt = hh*2 + qi (compile-time); lane(ql,l16) holds O[q][d = dt*16+ql*4+r]
      float ss = 0.f;
#pragma unroll
      for (int dt = 0; dt < 4; ++dt)
#pragma unroll
        for (int r = 0; r < 4; ++r) {
          float v = acc[dt][hh * 2 + qi][r];
          ss += v * v;
        }
      ss += __shfl_xor(ss, 16, 64);
      ss += __shfl_xor(ss, 32, 64);
      float nrm = sqrtf(ss);
      float sc = tanhf(nrm) / fmaxf(nrm, 1e-12f);
      int q = qw0 + (hh * 2 + qi) * 16 + l16;
      size_t gbase = ((size_t)(b * Nc + q)) * DIc + h * 80 + DKc;  // gate slice (fp16)
#pragma unroll
      for (int dt = 0; dt < 4; ++dt) {
        uint2 gu = *(const uint2*)&QG[gbase + dt * 16 + ql * 4];
        union { uint2 u; _Float16 hv[4]; } gv; gv.u = gu;
        float o[4];
#pragma unroll
        for (int r = 0; r < 4; ++r) {
          float x = (float)gv.hv[r];
          float av = acc[dt][hh * 2 + qi][r];
          float s = x / (1.f + __expf(-x));
          float e2 = __expf(2.f * s);
          float g = 1.f - 2.f / (e2 + 1.f);  // tanh(s)
          o[r] = av * sc * g;
        }
        uint2 w;
        w.x = pack2bf(o[0], o[1]);
        w.y = pack2bf(o[2], o[3]);
        *(uint2*)&of[wave * 32 + qi * 16 + l16][dt * 16 + ql * 4] = w;
      }
    }
    __syncthreads();
    {
      int row = tid >> 1, cb = (tid & 1) * 32;
      int q = q0 + (row >> 5) * 64 + hh * 32 + (row & 31);
      size_t obase = ((size_t)(b * Nc + q)) * (Hc * DVc) + h * DVc + cb;
#pragma unroll
      for (int i = 0; i < 4; ++i)
        *(ushort8*)&outpre[obase + i * 8] = *(const ushort8*)&of[row][cb + i * 8];
    }
  }
}

extern "C" void kernel_launch(void* const* d_in, const int* in_sizes, int n_in,
                              void* d_out, int out_size, void* d_ws, size_t ws_size,
                              hipStream_t stream) {
  const float* X = (const float*)d_in[0];     // (4,2048,1024)
  const float* Wqg = (const float*)d_in[1];   // (1024,1280)
  const float* Wkv = (const float*)d_in[2];   // (1024,1280)
  const float* Wout = (const float*)d_in[3];  // (1024,1024)
  float* out = (float*)d_out;
  (void)in_sizes; (void)n_in; (void)out_size; (void)ws_size;

  char* ws = (char*)d_ws;
  size_t off = 0;
  auto alloc = [&](size_t bytes) {
    void* p = ws + off;
    off += (bytes + 255) & ~(size_t)255;
    return p;
  };
  unsigned short* Xbf   = (unsigned short*)alloc((size_t)Mc * Dc * 2);            // 16 MB
  unsigned short* WqgT  = (unsigned short*)alloc((size_t)DIc * Dc * 2);           // 2.5 MB (WkvT MUST follow contiguously)
  unsigned short* WkvT  = (unsigned short*)alloc((size_t)DIc * Dc * 2);
  unsigned short* WoutT = (unsigned short*)alloc((size_t)Dc * Dc * 2);            // 2 MB
  unsigned short* QG    = (unsigned short*)alloc((size_t)Mc * DIc * 2);           // 20 MB (fp16)
  unsigned short* KV    = (unsigned short*)alloc((size_t)Mc * DIc * 2);           // 20 MB (fp16)
  unsigned short* Qn    = (unsigned short*)alloc((size_t)Bc * Hc * Nc * 16 * 2);  // 4 MB (fp16, unpadded)
  unsigned short* Kn    = (unsigned short*)alloc((size_t)Bc * Hc * Nc * 16 * 2);  // 4 MB
  unsigned short* Vtg   = (unsigned short*)alloc((size_t)Bc * Hc * Nc * DVc * 2); // 16 MB (fp16)
  unsigned short* outpre = Xbf;  // Xbf dead after projection GEMM; same size

  prep_kernel<<<4992, 256, 0, stream>>>(X, Xbf, Wqg, WqgT, Wkv, WkvT, Wout, WoutT);
  gemm_proj<<<Mc / 128 * (2 * DIc / 128), 256, 0, stream>>>(Xbf, WqgT, QG, KV, Dc);
  norm_kernel<<<(Mc * Hc) / 256, 256, 0, stream>>>(QG, KV, Qn, Kn, Vtg);
  attn_kernel<<<512, 256, 0, stream>>>(Qn, Kn, Vtg, QG, outpre);
  gemm_glds<<<Mc / 128 * (Dc / 128), 256, 0, stream>>>(outpre, WoutT, out, Mc, Dc, Dc);
}